// Round 1
// baseline (375.776 us; speedup 1.0000x reference)
//
#include <hip/hip_runtime.h>
#include <math.h>

#define DIMC 16
#define KB 8
// c = (XY_MAX - XY_MIN) - K*MIN_BW = 2 - 8*0.001
#define C_SCALE 1.992f
#define MIN_BW 0.001f
#define MIN_KS 0.001f

// jax.nn.softplus(v) == logaddexp(v, 0) == max(v,0) + log1p(exp(-|v|))
__device__ __forceinline__ float softplus_f(float v) {
    return fmaxf(v, 0.0f) + log1pf(expf(-fabsf(v)));
}

// jnp.mod(v, 2): remainder with sign of divisor (always >= 0 here)
__device__ __forceinline__ float mod2(float v) {
    float r = fmodf(v, 2.0f);
    if (r < 0.0f) r += 2.0f;
    return r;
}

__global__ __launch_bounds__(256) void spline_coupling_kernel(
    const float* __restrict__ X,
    const float* __restrict__ W,
    const float* __restrict__ H,
    const float* __restrict__ S,
    const float* __restrict__ SH,
    float* __restrict__ OUT,
    int m)
{
    const int total = m * DIMC;
    const int gid = blockIdx.x * blockDim.x + threadIdx.x;
    if (gid >= total) return;
    const int row = gid >> 4;   // / DIMC
    const int d   = gid & 15;   // % DIMC

    float x = X[gid];
    float ladJsum = 0.0f;

    #pragma unroll
    for (int t = 0; t < 2; ++t) {
        const size_t base = (size_t)t * m + row;
        const float4* wp = (const float4*)(W + base * (DIMC * KB) + d * KB);
        const float4* hp = (const float4*)(H + base * (DIMC * KB) + d * KB);
        const float*  sp = S + base * (DIMC * (KB - 1)) + d * (KB - 1);
        const float shift = SH[base * DIMC + d];

        // forward periodic shift: mod(x + shift - A, B-A) + A, A=-1,B=1
        x = mod2(x + shift + 1.0f) - 1.0f;

        float4 w0 = wp[0], w1 = wp[1];
        float4 h0 = hp[0], h1 = hp[1];
        float wv[KB] = {w0.x, w0.y, w0.z, w0.w, w1.x, w1.y, w1.z, w1.w};
        float hv[KB] = {h0.x, h0.y, h0.z, h0.w, h1.x, h1.y, h1.z, h1.w};

        // softmax(w) * c + MIN_BW  -> bin widths
        float mx = wv[0];
        #pragma unroll
        for (int j = 1; j < KB; ++j) mx = fmaxf(mx, wv[j]);
        float sum = 0.0f;
        #pragma unroll
        for (int j = 0; j < KB; ++j) { wv[j] = expf(wv[j] - mx); sum += wv[j]; }
        float inv = C_SCALE / sum;
        #pragma unroll
        for (int j = 0; j < KB; ++j) wv[j] = wv[j] * inv + MIN_BW;

        // softmax(h) * c + MIN_BW  -> bin heights
        mx = hv[0];
        #pragma unroll
        for (int j = 1; j < KB; ++j) mx = fmaxf(mx, hv[j]);
        sum = 0.0f;
        #pragma unroll
        for (int j = 0; j < KB; ++j) { hv[j] = expf(hv[j] - mx); sum += hv[j]; }
        inv = C_SCALE / sum;
        #pragma unroll
        for (int j = 0; j < KB; ++j) hv[j] = hv[j] * inv + MIN_BW;

        // Fused cumsum + bin search + gather. Knot positions are strictly
        // increasing, so idx = count(x >= xk[1..K-1]) = last j with x >= xk[j].
        // Selects (v_cndmask) instead of dynamic register indexing -> no scratch.
        int   idx = 0;
        float xk = -1.0f, yk = -1.0f;        // running knot position
        float x0 = -1.0f, y0 = -1.0f;
        float wk = wv[0], hk = hv[0];
        #pragma unroll
        for (int j = 1; j < KB; ++j) {
            xk += wv[j - 1];
            yk += hv[j - 1];
            bool ge = (x >= xk);
            idx = ge ? j     : idx;
            x0  = ge ? xk    : x0;
            y0  = ge ? yk    : y0;
            wk  = ge ? wv[j] : wk;
            hk  = ge ? hv[j] : hk;
        }

        // knot slopes: d[0]=d[K]=1, interior = softplus(s)+MIN_KS.
        // Only two s values are live; clamp addresses to stay in bounds.
        int i0 = idx - 1; if (i0 < 0) i0 = 0;
        int i1 = idx;     if (i1 > KB - 2) i1 = KB - 2;
        float s0 = sp[i0];
        float s1 = sp[i1];
        float d0 = (idx == 0)      ? 1.0f : softplus_f(s0) + MIN_KS;
        float d1 = (idx == KB - 1) ? 1.0f : softplus_f(s1) + MIN_KS;

        float sk  = hk / wk;
        float tt  = (x - x0) / wk;
        float omt = 1.0f - tt;
        float a2  = d1 + d0 - 2.0f * sk;
        float den = sk + a2 * tt * omt;
        float y   = y0 + hk * (sk * tt * tt + d0 * tt * omt) / den;
        float num = d1 * tt * tt + 2.0f * sk * tt * omt + d0 * omt * omt;
        float ladJ = 2.0f * logf(sk) + logf(num) - 2.0f * logf(den);
        ladJsum += ladJ;

        // inverse periodic shift
        x = mod2(y - shift + 1.0f) - 1.0f;
    }

    OUT[gid] = x;
    OUT[(size_t)total + gid] = ladJsum;
}

extern "C" void kernel_launch(void* const* d_in, const int* in_sizes, int n_in,
                              void* d_out, int out_size, void* d_ws, size_t ws_size,
                              hipStream_t stream) {
    const int total = in_sizes[0];        // m * DIM
    const int m = total / DIMC;
    const float* X  = (const float*)d_in[0];
    const float* W  = (const float*)d_in[1];
    const float* H  = (const float*)d_in[2];
    const float* S  = (const float*)d_in[3];
    const float* SH = (const float*)d_in[4];
    float* OUT = (float*)d_out;

    const int block = 256;
    const int grid = (total + block - 1) / block;
    spline_coupling_kernel<<<grid, block, 0, stream>>>(X, W, H, S, SH, OUT, m);
}

// Round 2
// 366.802 us; speedup vs baseline: 1.0245x; 1.0245x over previous
//
#include <hip/hip_runtime.h>
#include <math.h>

#define DIMC 16
#define KB 8
// c = (XY_MAX - XY_MIN) - K*MIN_BW = 2 - 8*0.001
#define C_SCALE 1.992f
#define MIN_BW 0.001f
#define MIN_KS 0.001f

#define LOG2E 1.44269504088896340736f
#define LN2   0.69314718055994530942f

__device__ __forceinline__ float fast_exp(float v) {
    return __builtin_amdgcn_exp2f(v * LOG2E);          // v_exp_f32
}
__device__ __forceinline__ float fast_log(float v) {
    return __builtin_amdgcn_logf(v) * LN2;             // v_log_f32
}
__device__ __forceinline__ float fast_rcp(float v) {
    return __builtin_amdgcn_rcpf(v);                   // v_rcp_f32
}

// softplus(v) = max(v,0) + log(1 + exp(-|v|)); 1+e in [1,2] so fast_log is safe
__device__ __forceinline__ float softplus_f(float v) {
    float e = fast_exp(-fabsf(v));
    return fmaxf(v, 0.0f) + fast_log(1.0f + e);
}

__global__ __launch_bounds__(256) void spline_coupling_kernel(
    const float* __restrict__ X,
    const float* __restrict__ W,
    const float* __restrict__ H,
    const float* __restrict__ S,
    const float* __restrict__ SH,
    float* __restrict__ OUT,
    int m)
{
    const int total = m * DIMC;
    const int gid = blockIdx.x * blockDim.x + threadIdx.x;
    if (gid >= total) return;
    const int row = gid >> 4;   // / DIMC
    const int d   = gid & 15;   // % DIMC

    float x = X[gid];
    float ladJsum = 0.0f;

    #pragma unroll
    for (int t = 0; t < 2; ++t) {
        const size_t base = (size_t)t * m + row;
        const float4* wp = (const float4*)(W + base * (DIMC * KB) + d * KB);
        const float4* hp = (const float4*)(H + base * (DIMC * KB) + d * KB);
        const float*  sp = S + base * (DIMC * (KB - 1)) + d * (KB - 1);
        const float shift = SH[base * DIMC + d];

        // forward periodic shift: mod(x+shift+1, 2) - 1.
        // x in [-1,1), shift in [0,1)  =>  v in [0,3): one conditional subtract.
        {
            float v = x + shift + 1.0f;
            if (v >= 2.0f) v -= 2.0f;
            x = v - 1.0f;
        }

        float4 w0 = wp[0], w1 = wp[1];
        float4 h0 = hp[0], h1 = hp[1];
        float wv[KB] = {w0.x, w0.y, w0.z, w0.w, w1.x, w1.y, w1.z, w1.w};
        float hv[KB] = {h0.x, h0.y, h0.z, h0.w, h1.x, h1.y, h1.z, h1.w};

        // softmax(w) * c + MIN_BW  -> bin widths
        float mx = wv[0];
        #pragma unroll
        for (int j = 1; j < KB; ++j) mx = fmaxf(mx, wv[j]);
        float sum = 0.0f;
        #pragma unroll
        for (int j = 0; j < KB; ++j) { wv[j] = fast_exp(wv[j] - mx); sum += wv[j]; }
        float inv = C_SCALE * fast_rcp(sum);
        #pragma unroll
        for (int j = 0; j < KB; ++j) wv[j] = wv[j] * inv + MIN_BW;

        // softmax(h) * c + MIN_BW  -> bin heights
        mx = hv[0];
        #pragma unroll
        for (int j = 1; j < KB; ++j) mx = fmaxf(mx, hv[j]);
        sum = 0.0f;
        #pragma unroll
        for (int j = 0; j < KB; ++j) { hv[j] = fast_exp(hv[j] - mx); sum += hv[j]; }
        inv = C_SCALE * fast_rcp(sum);
        #pragma unroll
        for (int j = 0; j < KB; ++j) hv[j] = hv[j] * inv + MIN_BW;

        // Fused cumsum + bin search + gather (select-based, no scratch).
        int   idx = 0;
        float xk = -1.0f, yk = -1.0f;        // running knot position
        float x0 = -1.0f, y0 = -1.0f;
        float wk = wv[0], hk = hv[0];
        #pragma unroll
        for (int j = 1; j < KB; ++j) {
            xk += wv[j - 1];
            yk += hv[j - 1];
            bool ge = (x >= xk);
            idx = ge ? j     : idx;
            x0  = ge ? xk    : x0;
            y0  = ge ? yk    : y0;
            wk  = ge ? wv[j] : wk;
            hk  = ge ? hv[j] : hk;
        }

        // knot slopes: d[0]=d[K]=1, interior = softplus(s)+MIN_KS.
        int i0 = idx - 1; if (i0 < 0) i0 = 0;
        int i1 = idx;     if (i1 > KB - 2) i1 = KB - 2;
        float s0 = sp[i0];
        float s1 = sp[i1];
        float d0 = (idx == 0)      ? 1.0f : softplus_f(s0) + MIN_KS;
        float d1 = (idx == KB - 1) ? 1.0f : softplus_f(s1) + MIN_KS;

        float rwk = fast_rcp(wk);
        float sk  = hk * rwk;
        float tt  = (x - x0) * rwk;
        float omt = 1.0f - tt;
        float a2  = d1 + d0 - 2.0f * sk;
        float den = sk + a2 * tt * omt;
        float rden = fast_rcp(den);
        float y   = y0 + hk * (sk * tt * tt + d0 * tt * omt) * rden;
        float num = d1 * tt * tt + 2.0f * sk * tt * omt + d0 * omt * omt;
        // ladJ = 2 log sk + log num - 2 log den = log(sk^2 * num * rden^2)
        float skr = sk * rden;
        ladJsum += fast_log(skr * skr * num);

        // inverse periodic shift: mod(y - shift + 1, 2) - 1, arg in (-1, 2].
        {
            float v = y - shift + 1.0f;
            if (v < 0.0f)  v += 2.0f;
            if (v >= 2.0f) v -= 2.0f;
            x = v - 1.0f;
        }
    }

    OUT[gid] = x;
    OUT[(size_t)total + gid] = ladJsum;
}

extern "C" void kernel_launch(void* const* d_in, const int* in_sizes, int n_in,
                              void* d_out, int out_size, void* d_ws, size_t ws_size,
                              hipStream_t stream) {
    const int total = in_sizes[0];        // m * DIM
    const int m = total / DIMC;
    const float* X  = (const float*)d_in[0];
    const float* W  = (const float*)d_in[1];
    const float* H  = (const float*)d_in[2];
    const float* S  = (const float*)d_in[3];
    const float* SH = (const float*)d_in[4];
    float* OUT = (float*)d_out;

    const int block = 256;
    const int grid = (total + block - 1) / block;
    spline_coupling_kernel<<<grid, block, 0, stream>>>(X, W, H, S, SH, OUT, m);
}